// Round 4
// baseline (7315.748 us; speedup 1.0000x reference)
//
#include <hip/hip_runtime.h>
#include <cstddef>

typedef __attribute__((ext_vector_type(8))) short short8;
typedef __attribute__((ext_vector_type(4))) short short4v;
typedef __attribute__((ext_vector_type(4))) float f32x4;
typedef __attribute__((ext_vector_type(2))) unsigned short u16x2;

__device__ __forceinline__ unsigned short f2bf(float f){
  unsigned u = __builtin_bit_cast(unsigned, f);
  u += 0x7FFFu + ((u >> 16) & 1u);          // round-to-nearest-even
  return (unsigned short)(u >> 16);
}
__device__ __forceinline__ float bf2f(unsigned short h){
  unsigned u = ((unsigned)h) << 16;
  return __builtin_bit_cast(float, u);
}
__device__ __forceinline__ float sigf(float x){
  return __builtin_amdgcn_rcpf(1.0f + __builtin_amdgcn_exp2f(-1.4426950408889634f * x));
}
__device__ __forceinline__ float tanhf_(float x){
  return 1.0f - 2.0f * __builtin_amdgcn_rcpf(1.0f + __builtin_amdgcn_exp2f(2.8853900817779268f * x));
}
__device__ __forceinline__ u16x2 min4(uint4 a){
  u16x2 x = __builtin_bit_cast(u16x2, a.x), y = __builtin_bit_cast(u16x2, a.y);
  u16x2 z = __builtin_bit_cast(u16x2, a.z), w = __builtin_bit_cast(u16x2, a.w);
  return __builtin_elementwise_min(__builtin_elementwise_min(x, y),
                                   __builtin_elementwise_min(z, w));
}

// inputs [32][1024][256] fp32 -> xbf [t*32+b][256] bf16
__global__ __launch_bounds__(64) void cast_x(const float* __restrict__ in, unsigned short* __restrict__ xb){
  int blk = blockIdx.x;              // b*1024 + t
  int t = blk & 1023, b = blk >> 10;
  int k = threadIdx.x * 4;
  float4 v = *(const float4*)(in + (size_t)blk * 256 + k);
  unsigned lo = f2bf(v.x) | ((unsigned)f2bf(v.y) << 16);
  unsigned hi = f2bf(v.z) | ((unsigned)f2bf(v.w) << 16);
  *(uint2*)(xb + ((size_t)t * 32 + b) * 256 + k) = make_uint2(lo, hi);
}

// Wih (fw,bw) fp32 -> Bw [2048][K] bf16 (row = dir*1024 + gatecol), bias[row] = bih+bhh
__global__ __launch_bounds__(64) void cast_w(const float* __restrict__ Wf, const float* __restrict__ Wb,
    const float* __restrict__ bihf, const float* __restrict__ bhhf,
    const float* __restrict__ bihb, const float* __restrict__ bhhb,
    unsigned short* __restrict__ Bw, float* __restrict__ bias, int K){
  int row = blockIdx.x;              // 0..2047
  int dd = row >> 10, gc = row & 1023;
  const float* src = (dd ? Wb : Wf) + (size_t)gc * K;
  unsigned short* dst = Bw + (size_t)row * K;
  for (int k = threadIdx.x * 4; k < K; k += 256){
    float4 v = *(const float4*)(src + k);
    unsigned lo = f2bf(v.x) | ((unsigned)f2bf(v.y) << 16);
    unsigned hi = f2bf(v.z) | ((unsigned)f2bf(v.w) << 16);
    *(uint2*)(dst + k) = make_uint2(lo, hi);
  }
  if (threadIdx.x == 0)
    bias[row] = dd ? (bihb[gc] + bhhb[gc]) : (bihf[gc] + bhhf[gc]);
}

// C[row=t*32+b][col 0..2047] = A[row][K] @ Bw[col][K]^T + bias[col], stored xg[t][col][b] bf16
__global__ __launch_bounds__(256) void gemm_xg(const unsigned short* __restrict__ A,
    const unsigned short* __restrict__ Bw, const float* __restrict__ bias,
    unsigned short* __restrict__ xg, int K){
  __shared__ __align__(16) unsigned short Al[128 * 64];
  __shared__ __align__(16) unsigned short Bl[128 * 64];
  const int tid = threadIdx.x;
  const int w = tid >> 6, l = tid & 63, q = l >> 4, cl = l & 15;
  const int bm = blockIdx.x >> 4, bn = blockIdx.x & 15;
  const int wm = w & 1, wn = w >> 1;
  f32x4 acc[4][4];
#pragma unroll
  for (int nt = 0; nt < 4; ++nt){
    float bv = bias[bn * 128 + wn * 64 + nt * 16 + cl];
#pragma unroll
    for (int mt = 0; mt < 4; ++mt) acc[mt][nt] = (f32x4){bv, bv, bv, bv};
  }
  const unsigned short* Ab = A + (size_t)(bm * 128) * K;
  const unsigned short* Bb = Bw + (size_t)(bn * 128) * K;
  for (int k0 = 0; k0 < K; k0 += 64){
#pragma unroll
    for (int i = 0; i < 4; ++i){
      int task = tid + i * 256;
      int row = task >> 3, ch = task & 7;
      int sw = ((ch ^ (row & 7)) * 8);
      *(uint4*)(&Al[row * 64 + sw]) = *(const uint4*)(Ab + (size_t)row * K + k0 + ch * 8);
      *(uint4*)(&Bl[row * 64 + sw]) = *(const uint4*)(Bb + (size_t)row * K + k0 + ch * 8);
    }
    __syncthreads();
#pragma unroll
    for (int kt2 = 0; kt2 < 2; ++kt2){
      short8 af[4], bfv[4];
#pragma unroll
      for (int mt = 0; mt < 4; ++mt){
        int row = wm * 64 + mt * 16 + cl;
        af[mt] = *(const short8*)(&Al[row * 64 + (((kt2 * 4 + q) ^ (row & 7)) * 8)]);
      }
#pragma unroll
      for (int nt = 0; nt < 4; ++nt){
        int n = wn * 64 + nt * 16 + cl;
        bfv[nt] = *(const short8*)(&Bl[n * 64 + (((kt2 * 4 + q) ^ (n & 7)) * 8)]);
      }
#pragma unroll
      for (int mt = 0; mt < 4; ++mt)
#pragma unroll
        for (int nt = 0; nt < 4; ++nt)
          acc[mt][nt] = __builtin_amdgcn_mfma_f32_16x16x32_bf16(af[mt], bfv[nt], acc[mt][nt], 0, 0, 0);
    }
    __syncthreads();
  }
#pragma unroll
  for (int mt = 0; mt < 4; ++mt){
    int row = bm * 128 + wm * 64 + mt * 16 + q * 4;
    int tt = row >> 5, bb = row & 31;
#pragma unroll
    for (int nt = 0; nt < 4; ++nt){
      int col = bn * 128 + wn * 64 + nt * 16 + cl;
      f32x4 v = acc[mt][nt];
      unsigned lo = f2bf(v[0]) | ((unsigned)f2bf(v[1]) << 16);
      unsigned hi = f2bf(v[2]) | ((unsigned)f2bf(v[3]) << 16);
      *(uint2*)(xg + ((size_t)tt * 2048 + col) * 32 + bb) = make_uint2(lo, hi);
    }
  }
}

// Recurrent core, tag-in-data + barrier-free autonomous waves.
// Grid = 32 blocks: unit u = blockIdx%8 (dir = u>>2, batch grp = u&3, 8 batches),
// slice s = blockIdx>>3 owns hidden cols [s*64, s*64+64); wave w owns 16 of them.
// hx per unit: [slot(2)][row m(8)][k(256)] u32, each u32 = (h_bf16 << 16) | (tag16 = t+1).
// Each wave directly polls the 64 granules its A-frags need (row = lane&7, k = quad*8+kt*32,
// 16x dwordx4 sc1 off one base addr), validates all 64 tags via v_pk_min_u16 tree, then
// unpacks in-register and MFMAs. NO LDS relay, NO __syncthreads in the loop: waves
// self-synchronize on data arrival (no retry-quantization overshoot). Slot reuse is
// race-free: every consumer reads ALL k, so a producer's t+2 store data depends (true
// data dep) on tags t+2 from all 16 unit waves, each published only after their slot reads.
__global__ __launch_bounds__(256, 1) void lstm_rec(const unsigned short* __restrict__ xg,
    const float* __restrict__ WhhF, const float* __restrict__ WhhB,
    const float* __restrict__ mask, unsigned* __restrict__ hx,
    unsigned short* __restrict__ houts, float* __restrict__ out,
    float* __restrict__ hnout, float* __restrict__ cnout, int layer){
  __shared__ float maskL[8192];            // [t(1024)][row(8)]
  const int tid = threadIdx.x;
  const int w = tid >> 6, l = tid & 63, q = l >> 4, cl = l & 15;
  const int u = blockIdx.x & 7, s = blockIdx.x >> 3;
  const int d = u >> 2, b0 = (u & 3) * 8;
  const float* __restrict__ Whh = d ? WhhB : WhhF;
  const int jj = s * 64 + w * 16 + cl;     // hidden col owned by this lane
  short8 bfrag[4][8];                      // Whh B-fragments: [gate][ktile], 128 VGPRs
#pragma unroll
  for (int gi = 0; gi < 4; ++gi){
    const float* wr = Whh + (size_t)(gi * 256 + jj) * 256 + q * 8;
#pragma unroll
    for (int kt = 0; kt < 8; ++kt){
      float4 x0 = *(const float4*)(wr + kt * 32);
      float4 x1 = *(const float4*)(wr + kt * 32 + 4);
      short8 f;
      f[0] = (short)f2bf(x0.x); f[1] = (short)f2bf(x0.y); f[2] = (short)f2bf(x0.z); f[3] = (short)f2bf(x0.w);
      f[4] = (short)f2bf(x1.x); f[5] = (short)f2bf(x1.y); f[6] = (short)f2bf(x1.z); f[7] = (short)f2bf(x1.w);
      bfrag[gi][kt] = f;
    }
  }
  // mask -> LDS, layout [t][row] for bank-broadcast reads
  for (int idx = tid; idx < 8192; idx += 256){
    int tt = idx >> 3, r = idx & 7;
    maskL[idx] = mask[(size_t)(b0 + r) * 1024 + tt];
  }
  __syncthreads();
  float cst[4] = {0.f, 0.f, 0.f, 0.f};
  unsigned* hxu = hx + (size_t)u * 4096;   // [slot(2)][m(8)][k(256)] u32
  const bool qv = (q < 2);
  const int bq = b0 + q * 4;
  for (int t = 0; t < 1024; ++t){
    const int ot = d ? (1023 - t) : t;
    const int par = t & 1;
    f32x4 acc[4];
    if (qv){
#pragma unroll
      for (int gi = 0; gi < 4; ++gi){
        const unsigned short* xp = xg + ((size_t)ot * 2048 + (d * 1024 + gi * 256 + jj)) * 32 + bq;
        short4v xv = *(const short4v*)xp;
        acc[gi] = (f32x4){bf2f((unsigned short)xv[0]), bf2f((unsigned short)xv[1]),
                          bf2f((unsigned short)xv[2]), bf2f((unsigned short)xv[3])};
      }
    } else {
#pragma unroll
      for (int gi = 0; gi < 4; ++gi) acc[gi] = (f32x4){0.f, 0.f, 0.f, 0.f};
    }
    if (t > 0){
      // poll own A-granules: row = cl&7, k = q*8 + kt*32 + j, j=0..7 -> 16x dwordx4
      const unsigned* base = hxu + (size_t)(par ^ 1) * 2048 + (size_t)(cl & 7) * 256 + q * 8;
      const unsigned short tagv = (unsigned short)t;
      uint4 g0,g1,g2,g3,g4,g5,g6,g7,g8,g9,g10,g11,g12,g13,g14,g15;
      while (true){
        asm volatile(
          "global_load_dwordx4 %0, %16, off sc1\n\t"
          "global_load_dwordx4 %1, %16, off offset:16 sc1\n\t"
          "global_load_dwordx4 %2, %16, off offset:128 sc1\n\t"
          "global_load_dwordx4 %3, %16, off offset:144 sc1\n\t"
          "global_load_dwordx4 %4, %16, off offset:256 sc1\n\t"
          "global_load_dwordx4 %5, %16, off offset:272 sc1\n\t"
          "global_load_dwordx4 %6, %16, off offset:384 sc1\n\t"
          "global_load_dwordx4 %7, %16, off offset:400 sc1\n\t"
          "global_load_dwordx4 %8, %16, off offset:512 sc1\n\t"
          "global_load_dwordx4 %9, %16, off offset:528 sc1\n\t"
          "global_load_dwordx4 %10, %16, off offset:640 sc1\n\t"
          "global_load_dwordx4 %11, %16, off offset:656 sc1\n\t"
          "global_load_dwordx4 %12, %16, off offset:768 sc1\n\t"
          "global_load_dwordx4 %13, %16, off offset:784 sc1\n\t"
          "global_load_dwordx4 %14, %16, off offset:896 sc1\n\t"
          "global_load_dwordx4 %15, %16, off offset:912 sc1\n\t"
          "s_waitcnt vmcnt(0)"
          : "=v"(g0),"=v"(g1),"=v"(g2),"=v"(g3),"=v"(g4),"=v"(g5),"=v"(g6),"=v"(g7),
            "=v"(g8),"=v"(g9),"=v"(g10),"=v"(g11),"=v"(g12),"=v"(g13),"=v"(g14),"=v"(g15)
          : "v"(base)
          : "memory");
        u16x2 m = __builtin_elementwise_min(
          __builtin_elementwise_min(
            __builtin_elementwise_min(__builtin_elementwise_min(min4(g0), min4(g1)),
                                      __builtin_elementwise_min(min4(g2), min4(g3))),
            __builtin_elementwise_min(__builtin_elementwise_min(min4(g4), min4(g5)),
                                      __builtin_elementwise_min(min4(g6), min4(g7)))),
          __builtin_elementwise_min(
            __builtin_elementwise_min(__builtin_elementwise_min(min4(g8), min4(g9)),
                                      __builtin_elementwise_min(min4(g10), min4(g11))),
            __builtin_elementwise_min(__builtin_elementwise_min(min4(g12), min4(g13)),
                                      __builtin_elementwise_min(min4(g14), min4(g15)))));
        if (__all(m[0] >= tagv)) break;
      }
      // unpack h (high 16 bits) into A-frags
      uint4 ga[8] = { (uint4){g0.x,g0.y,g0.z,g0.w}, (uint4){g2.x,g2.y,g2.z,g2.w},
                      (uint4){g4.x,g4.y,g4.z,g4.w}, (uint4){g6.x,g6.y,g6.z,g6.w},
                      (uint4){g8.x,g8.y,g8.z,g8.w}, (uint4){g10.x,g10.y,g10.z,g10.w},
                      (uint4){g12.x,g12.y,g12.z,g12.w}, (uint4){g14.x,g14.y,g14.z,g14.w} };
      uint4 gb[8] = { (uint4){g1.x,g1.y,g1.z,g1.w}, (uint4){g3.x,g3.y,g3.z,g3.w},
                      (uint4){g5.x,g5.y,g5.z,g5.w}, (uint4){g7.x,g7.y,g7.z,g7.w},
                      (uint4){g9.x,g9.y,g9.z,g9.w}, (uint4){g11.x,g11.y,g11.z,g11.w},
                      (uint4){g13.x,g13.y,g13.z,g13.w}, (uint4){g15.x,g15.y,g15.z,g15.w} };
      short8 af[8];
#pragma unroll
      for (int kt = 0; kt < 8; ++kt){
        uint4 p;
        p.x = (ga[kt].x >> 16) | (ga[kt].y & 0xFFFF0000u);
        p.y = (ga[kt].z >> 16) | (ga[kt].w & 0xFFFF0000u);
        p.z = (gb[kt].x >> 16) | (gb[kt].y & 0xFFFF0000u);
        p.w = (gb[kt].z >> 16) | (gb[kt].w & 0xFFFF0000u);
        af[kt] = __builtin_bit_cast(short8, p);
      }
#pragma unroll
      for (int kt = 0; kt < 8; ++kt)
#pragma unroll
        for (int gi = 0; gi < 4; ++gi)
          acc[gi] = __builtin_amdgcn_mfma_f32_16x16x32_bf16(af[kt], bfrag[gi][kt], acc[gi], 0, 0, 0);
    }
    if (qv){
      float hv[4];
      unsigned short hb[4];
#pragma unroll
      for (int r = 0; r < 4; ++r){
        float mvr = maskL[ot * 8 + q * 4 + r];
        float ig = sigf(acc[0][r]);
        float fg = sigf(acc[1][r]);
        float gg = tanhf_(acc[2][r]);
        float og = sigf(acc[3][r]);
        float cn = fg * cst[r] + ig * gg;
        float hn = og * tanhf_(cn);
        hn *= mvr; cn *= mvr;
        cst[r] = cn; hv[r] = hn; hb[r] = f2bf(hn);
      }
      const unsigned tagn = (unsigned)(t + 1);
      unsigned* sw = hxu + (size_t)par * 2048 + (size_t)(q * 4) * 256 + jj;
#pragma unroll
      for (int r = 0; r < 4; ++r)
        __hip_atomic_store(sw + r * 256, ((unsigned)hb[r] << 16) | tagn,
                           __ATOMIC_RELAXED, __HIP_MEMORY_SCOPE_AGENT);
      if (layer == 0){
#pragma unroll
        for (int r = 0; r < 4; ++r)
          houts[((size_t)ot * 32 + bq + r) * 512 + d * 256 + jj] = hb[r];
      } else {
#pragma unroll
        for (int r = 0; r < 4; ++r)
          out[((size_t)(bq + r) * 1024 + ot) * 512 + d * 256 + jj] = hv[r];
      }
      if (t == 1023){
#pragma unroll
        for (int r = 0; r < 4; ++r){
          size_t bo = (size_t)(layer * 32 + bq + r) * 512 + d * 256 + jj;
          hnout[bo] = hv[r];
          cnout[bo] = cst[r];
        }
      }
    }
  }
}

extern "C" void kernel_launch(void* const* d_in, const int* in_sizes, int n_in,
                              void* d_out, int out_size, void* d_ws, size_t ws_size,
                              hipStream_t stream){
  const float* inputs  = (const float*)d_in[0];
  const float* mask    = (const float*)d_in[1];
  const float* l0f_Wih = (const float*)d_in[2];
  const float* l0f_Whh = (const float*)d_in[3];
  const float* l0f_bih = (const float*)d_in[4];
  const float* l0f_bhh = (const float*)d_in[5];
  const float* l0b_Wih = (const float*)d_in[6];
  const float* l0b_Whh = (const float*)d_in[7];
  const float* l0b_bih = (const float*)d_in[8];
  const float* l0b_bhh = (const float*)d_in[9];
  const float* l1f_Wih = (const float*)d_in[10];
  const float* l1f_Whh = (const float*)d_in[11];
  const float* l1f_bih = (const float*)d_in[12];
  const float* l1f_bhh = (const float*)d_in[13];
  const float* l1b_Wih = (const float*)d_in[14];
  const float* l1b_Whh = (const float*)d_in[15];
  const float* l1b_bih = (const float*)d_in[16];
  const float* l1b_bhh = (const float*)d_in[17];

  char* ws = (char*)d_ws;
  unsigned short* xg   = (unsigned short*)(ws);                 // [1024][2048][32] bf16, 134217728 B
  unsigned short* xbf  = (unsigned short*)(ws + 134217728);     // [32768][256]  bf16, 16777216 B
  unsigned short* hout = (unsigned short*)(ws + 150994944);     // [32768][512]  bf16, 33554432 B
  unsigned short* B0   = (unsigned short*)(ws + 184549376);     // [2048][256]   bf16, 1048576 B
  unsigned short* B1   = (unsigned short*)(ws + 185597952);     // [2048][512]   bf16, 2097152 B
  float* bias0         = (float*)(ws + 187695104);              // [2048] f32
  float* bias1         = (float*)(ws + 187703296);              // [2048] f32
  unsigned* hx         = (unsigned*)(ws + 187711488);           // 2 layers x [8][2][8][256] u32 = 262144 B

  float* out   = (float*)d_out;          // [32][1024][512]
  float* hnout = out + 16777216;         // [2][32][512]
  float* cnout = hnout + 32768;          // [2][32][512]

  hipMemsetAsync(hx, 0, 262144, stream);  // tag16 = 0, never matches tags 1..1024
  cast_x<<<32768, 64, 0, stream>>>(inputs, xbf);
  cast_w<<<2048, 64, 0, stream>>>(l0f_Wih, l0b_Wih, l0f_bih, l0f_bhh, l0b_bih, l0b_bhh, B0, bias0, 256);
  cast_w<<<2048, 64, 0, stream>>>(l1f_Wih, l1b_Wih, l1f_bih, l1f_bhh, l1b_bih, l1b_bhh, B1, bias1, 512);
  gemm_xg<<<4096, 256, 0, stream>>>(xbf, B0, bias0, xg, 256);
  lstm_rec<<<32, 256, 0, stream>>>(xg, l0f_Whh, l0b_Whh, mask, hx, hout, nullptr, hnout, cnout, 0);
  gemm_xg<<<4096, 256, 0, stream>>>(hout, B1, bias1, xg, 512);
  lstm_rec<<<32, 256, 0, stream>>>(xg, l1f_Whh, l1b_Whh, mask, hx + 32768, nullptr, out, hnout, cnout, 1);
}

// Round 6
// 4496.632 us; speedup vs baseline: 1.6269x; 1.6269x over previous
//
#include <hip/hip_runtime.h>
#include <cstddef>

typedef __attribute__((ext_vector_type(8))) short short8;
typedef __attribute__((ext_vector_type(4))) short short4v;
typedef __attribute__((ext_vector_type(4))) float f32x4;
typedef __attribute__((ext_vector_type(2))) unsigned short u16x2;

__device__ __forceinline__ unsigned short f2bf(float f){
  unsigned u = __builtin_bit_cast(unsigned, f);
  u += 0x7FFFu + ((u >> 16) & 1u);          // round-to-nearest-even
  return (unsigned short)(u >> 16);
}
__device__ __forceinline__ float bf2f(unsigned short h){
  unsigned u = ((unsigned)h) << 16;
  return __builtin_bit_cast(float, u);
}
__device__ __forceinline__ float sigf(float x){
  return __builtin_amdgcn_rcpf(1.0f + __builtin_amdgcn_exp2f(-1.4426950408889634f * x));
}
__device__ __forceinline__ float tanhf_(float x){
  return 1.0f - 2.0f * __builtin_amdgcn_rcpf(1.0f + __builtin_amdgcn_exp2f(2.8853900817779268f * x));
}
__device__ __forceinline__ u16x2 min4(uint4 a){
  u16x2 x = __builtin_bit_cast(u16x2, a.x), y = __builtin_bit_cast(u16x2, a.y);
  u16x2 z = __builtin_bit_cast(u16x2, a.z), w = __builtin_bit_cast(u16x2, a.w);
  return __builtin_elementwise_min(__builtin_elementwise_min(x, y),
                                   __builtin_elementwise_min(z, w));
}

// inputs [32][1024][256] fp32 -> xbf [t*32+b][256] bf16
__global__ __launch_bounds__(64) void cast_x(const float* __restrict__ in, unsigned short* __restrict__ xb){
  int blk = blockIdx.x;              // b*1024 + t
  int t = blk & 1023, b = blk >> 10;
  int k = threadIdx.x * 4;
  float4 v = *(const float4*)(in + (size_t)blk * 256 + k);
  unsigned lo = f2bf(v.x) | ((unsigned)f2bf(v.y) << 16);
  unsigned hi = f2bf(v.z) | ((unsigned)f2bf(v.w) << 16);
  *(uint2*)(xb + ((size_t)t * 32 + b) * 256 + k) = make_uint2(lo, hi);
}

// Wih (fw,bw) fp32 -> Bw [2048][K] bf16 (row = dir*1024 + gatecol), bias[row] = bih+bhh
__global__ __launch_bounds__(64) void cast_w(const float* __restrict__ Wf, const float* __restrict__ Wb,
    const float* __restrict__ bihf, const float* __restrict__ bhhf,
    const float* __restrict__ bihb, const float* __restrict__ bhhb,
    unsigned short* __restrict__ Bw, float* __restrict__ bias, int K){
  int row = blockIdx.x;              // 0..2047
  int dd = row >> 10, gc = row & 1023;
  const float* src = (dd ? Wb : Wf) + (size_t)gc * K;
  unsigned short* dst = Bw + (size_t)row * K;
  for (int k = threadIdx.x * 4; k < K; k += 256){
    float4 v = *(const float4*)(src + k);
    unsigned lo = f2bf(v.x) | ((unsigned)f2bf(v.y) << 16);
    unsigned hi = f2bf(v.z) | ((unsigned)f2bf(v.w) << 16);
    *(uint2*)(dst + k) = make_uint2(lo, hi);
  }
  if (threadIdx.x == 0)
    bias[row] = dd ? (bihb[gc] + bhhb[gc]) : (bihf[gc] + bhhf[gc]);
}

// C[row=t*32+b][col 0..2047] = A[row][K] @ Bw[col][K]^T + bias[col], stored xg[t][col][b] bf16
__global__ __launch_bounds__(256) void gemm_xg(const unsigned short* __restrict__ A,
    const unsigned short* __restrict__ Bw, const float* __restrict__ bias,
    unsigned short* __restrict__ xg, int K){
  __shared__ __align__(16) unsigned short Al[128 * 64];
  __shared__ __align__(16) unsigned short Bl[128 * 64];
  const int tid = threadIdx.x;
  const int w = tid >> 6, l = tid & 63, q = l >> 4, cl = l & 15;
  const int bm = blockIdx.x >> 4, bn = blockIdx.x & 15;
  const int wm = w & 1, wn = w >> 1;
  f32x4 acc[4][4];
#pragma unroll
  for (int nt = 0; nt < 4; ++nt){
    float bv = bias[bn * 128 + wn * 64 + nt * 16 + cl];
#pragma unroll
    for (int mt = 0; mt < 4; ++mt) acc[mt][nt] = (f32x4){bv, bv, bv, bv};
  }
  const unsigned short* Ab = A + (size_t)(bm * 128) * K;
  const unsigned short* Bb = Bw + (size_t)(bn * 128) * K;
  for (int k0 = 0; k0 < K; k0 += 64){
#pragma unroll
    for (int i = 0; i < 4; ++i){
      int task = tid + i * 256;
      int row = task >> 3, ch = task & 7;
      int sw = ((ch ^ (row & 7)) * 8);
      *(uint4*)(&Al[row * 64 + sw]) = *(const uint4*)(Ab + (size_t)row * K + k0 + ch * 8);
      *(uint4*)(&Bl[row * 64 + sw]) = *(const uint4*)(Bb + (size_t)row * K + k0 + ch * 8);
    }
    __syncthreads();
#pragma unroll
    for (int kt2 = 0; kt2 < 2; ++kt2){
      short8 af[4], bfv[4];
#pragma unroll
      for (int mt = 0; mt < 4; ++mt){
        int row = wm * 64 + mt * 16 + cl;
        af[mt] = *(const short8*)(&Al[row * 64 + (((kt2 * 4 + q) ^ (row & 7)) * 8)]);
      }
#pragma unroll
      for (int nt = 0; nt < 4; ++nt){
        int n = wn * 64 + nt * 16 + cl;
        bfv[nt] = *(const short8*)(&Bl[n * 64 + (((kt2 * 4 + q) ^ (n & 7)) * 8)]);
      }
#pragma unroll
      for (int mt = 0; mt < 4; ++mt)
#pragma unroll
        for (int nt = 0; nt < 4; ++nt)
          acc[mt][nt] = __builtin_amdgcn_mfma_f32_16x16x32_bf16(af[mt], bfv[nt], acc[mt][nt], 0, 0, 0);
    }
    __syncthreads();
  }
#pragma unroll
  for (int mt = 0; mt < 4; ++mt){
    int row = bm * 128 + wm * 64 + mt * 16 + q * 4;
    int tt = row >> 5, bb = row & 31;
#pragma unroll
    for (int nt = 0; nt < 4; ++nt){
      int col = bn * 128 + wn * 64 + nt * 16 + cl;
      f32x4 v = acc[mt][nt];
      unsigned lo = f2bf(v[0]) | ((unsigned)f2bf(v[1]) << 16);
      unsigned hi = f2bf(v[2]) | ((unsigned)f2bf(v[3]) << 16);
      *(uint2*)(xg + ((size_t)tt * 2048 + col) * 32 + bb) = make_uint2(lo, hi);
    }
  }
}

// Recurrent core: tag-in-data (sc1/LLC, placement-agnostic) + per-wave quarter-polls +
// intra-CU LDS relay with monotone per-wave LDS flags. NO block barrier in the loop.
// Grid = 32 blocks: unit u = blockIdx%8 (dir=u>>2, batch grp=u&3), slice s = blockIdx>>3.
// hx per unit: [slot(2)][row m(8)][k(256)] u32 = (h_bf16<<16) | (tag16 = t+1).
// Wave w polls k-tiles {2w,2w+1} only (lanes cl<8: 4x dwordx4 sc1, EARLY-CLOBBERED asm,
// s_sleep backoff) -> writes packed h to LDS [par][kt][row][q] (80B row pitch, conflict-free)
// -> lgkmcnt(0) -> LDS flag[par][w]=t. All waves spin on the 4 flags, read full A-frags
// from LDS, MFMA. Slot-reuse chain: a wave's slot-p store at t is ordered behind all 4 LDS
// flags(t) <= each sibling's direct tag-t verification of one producer block <= union covers
// all 16 producer waves <= each published tag t only after its slot-p reads completed.
__global__ __launch_bounds__(256, 1) void lstm_rec(const unsigned short* __restrict__ xg,
    const float* __restrict__ WhhF, const float* __restrict__ WhhB,
    const float* __restrict__ mask, unsigned* __restrict__ hx,
    unsigned short* __restrict__ houts, float* __restrict__ out,
    float* __restrict__ hnout, float* __restrict__ cnout, int layer){
  __shared__ float maskL[8192];                       // [t(1024)][row(8)]
  __shared__ __align__(16) unsigned char AbufB[2 * 5120]; // [par][kt(8)][row(8) pitch 80B][q*16B]
  __shared__ int lflag[8];                            // [par][wave]
  const int tid = threadIdx.x;
  const int w = tid >> 6, l = tid & 63, q = l >> 4, cl = l & 15;
  const int u = blockIdx.x & 7, s = blockIdx.x >> 3;
  const int d = u >> 2, b0 = (u & 3) * 8;
  const float* __restrict__ Whh = d ? WhhB : WhhF;
  const int jj = s * 64 + w * 16 + cl;                // hidden col owned by this lane
  short8 bfrag[4][8];                                 // Whh B-frags: [gate][ktile], 128 VGPRs
#pragma unroll
  for (int gi = 0; gi < 4; ++gi){
    const float* wr = Whh + (size_t)(gi * 256 + jj) * 256 + q * 8;
#pragma unroll
    for (int kt = 0; kt < 8; ++kt){
      float4 x0 = *(const float4*)(wr + kt * 32);
      float4 x1 = *(const float4*)(wr + kt * 32 + 4);
      short8 f;
      f[0] = (short)f2bf(x0.x); f[1] = (short)f2bf(x0.y); f[2] = (short)f2bf(x0.z); f[3] = (short)f2bf(x0.w);
      f[4] = (short)f2bf(x1.x); f[5] = (short)f2bf(x1.y); f[6] = (short)f2bf(x1.z); f[7] = (short)f2bf(x1.w);
      bfrag[gi][kt] = f;
    }
  }
  if (tid < 8) lflag[tid] = 0;
  for (int idx = tid; idx < 8192; idx += 256){
    int tt = idx >> 3, r = idx & 7;
    maskL[idx] = mask[(size_t)(b0 + r) * 1024 + tt];
  }
  __syncthreads();
  float cst[4] = {0.f, 0.f, 0.f, 0.f};
  unsigned* hxu = hx + (size_t)u * 4096;              // [slot(2)][m(8)][k(256)] u32
  const bool qv = (q < 2);
  const int bq = b0 + q * 4;
  const int row8 = cl & 7;
  for (int t = 0; t < 1024; ++t){
    const int ot = d ? (1023 - t) : t;
    const int par = t & 1;
    f32x4 acc[4];
    if (qv){
#pragma unroll
      for (int gi = 0; gi < 4; ++gi){
        const unsigned short* xp = xg + ((size_t)ot * 2048 + (d * 1024 + gi * 256 + jj)) * 32 + bq;
        short4v xv = *(const short4v*)xp;
        acc[gi] = (f32x4){bf2f((unsigned short)xv[0]), bf2f((unsigned short)xv[1]),
                          bf2f((unsigned short)xv[2]), bf2f((unsigned short)xv[3])};
      }
    } else {
#pragma unroll
      for (int gi = 0; gi < 4; ++gi) acc[gi] = (f32x4){0.f, 0.f, 0.f, 0.f};
    }
    if (t > 0){
      if (cl < 8){
        // poll own quarter: rows cl, k-tiles {2w, 2w+1}, k-local q*8..q*8+7
        const unsigned* base = hxu + (size_t)(par ^ 1) * 2048 + (size_t)row8 * 256 + q * 8 + w * 64;
        const unsigned short tagv = (unsigned short)t;
        uint4 ga, gb, gc, gd;
        int guard = 0;
        while (true){
          asm volatile(
            "global_load_dwordx4 %0, %4, off sc1\n\t"
            "global_load_dwordx4 %1, %4, off offset:16 sc1\n\t"
            "global_load_dwordx4 %2, %4, off offset:128 sc1\n\t"
            "global_load_dwordx4 %3, %4, off offset:144 sc1\n\t"
            "s_waitcnt vmcnt(0)"
            : "=&v"(ga), "=&v"(gb), "=&v"(gc), "=&v"(gd)
            : "v"(base)
            : "memory");
          u16x2 m = __builtin_elementwise_min(__builtin_elementwise_min(min4(ga), min4(gb)),
                                              __builtin_elementwise_min(min4(gc), min4(gd)));
          if (__all(m[0] >= tagv)) break;
          if (++guard > (1 << 20)) break;   // hang-bail (wrong answer beats deadlock)
          __builtin_amdgcn_s_sleep(1);
        }
        // pack h (high 16b) and relay to LDS
        uint4 p0, p1;
        p0.x = (ga.x >> 16) | (ga.y & 0xFFFF0000u); p0.y = (ga.z >> 16) | (ga.w & 0xFFFF0000u);
        p0.z = (gb.x >> 16) | (gb.y & 0xFFFF0000u); p0.w = (gb.z >> 16) | (gb.w & 0xFFFF0000u);
        p1.x = (gc.x >> 16) | (gc.y & 0xFFFF0000u); p1.y = (gc.z >> 16) | (gc.w & 0xFFFF0000u);
        p1.z = (gd.x >> 16) | (gd.y & 0xFFFF0000u); p1.w = (gd.z >> 16) | (gd.w & 0xFFFF0000u);
        *(uint4*)(&AbufB[par * 5120 + (2 * w) * 640 + row8 * 80 + q * 16]) = p0;
        *(uint4*)(&AbufB[par * 5120 + (2 * w + 1) * 640 + row8 * 80 + q * 16]) = p1;
      }
      asm volatile("s_waitcnt lgkmcnt(0)" ::: "memory");
      if (l == 0)
        ((volatile int*)lflag)[par * 4 + w] = t;
      {
        volatile int* vf = (volatile int*)lflag + par * 4;
        int guard = 0;
        while (vf[0] < t || vf[1] < t || vf[2] < t || vf[3] < t){
          if (++guard > (1 << 24)) break;
        }
      }
      asm volatile("" ::: "memory");
      short8 af[8];
#pragma unroll
      for (int kt = 0; kt < 8; ++kt)
        af[kt] = *(const short8*)(&AbufB[par * 5120 + kt * 640 + row8 * 80 + q * 16]);
#pragma unroll
      for (int kt = 0; kt < 8; ++kt)
#pragma unroll
        for (int gi = 0; gi < 4; ++gi)
          acc[gi] = __builtin_amdgcn_mfma_f32_16x16x32_bf16(af[kt], bfrag[gi][kt], acc[gi], 0, 0, 0);
    }
    if (qv){
      float hv[4];
      unsigned short hb[4];
#pragma unroll
      for (int r = 0; r < 4; ++r){
        float mvr = maskL[ot * 8 + q * 4 + r];
        float ig = sigf(acc[0][r]);
        float fg = sigf(acc[1][r]);
        float gg = tanhf_(acc[2][r]);
        float og = sigf(acc[3][r]);
        float cn = fg * cst[r] + ig * gg;
        float hn = og * tanhf_(cn);
        hn *= mvr; cn *= mvr;
        cst[r] = cn; hv[r] = hn; hb[r] = f2bf(hn);
      }
      const unsigned tagn = (unsigned)(t + 1);
      unsigned* sw = hxu + (size_t)par * 2048 + (size_t)(q * 4) * 256 + jj;
#pragma unroll
      for (int r = 0; r < 4; ++r)
        __hip_atomic_store(sw + r * 256, ((unsigned)hb[r] << 16) | tagn,
                           __ATOMIC_RELAXED, __HIP_MEMORY_SCOPE_AGENT);
      if (layer == 0){
#pragma unroll
        for (int r = 0; r < 4; ++r)
          houts[((size_t)ot * 32 + bq + r) * 512 + d * 256 + jj] = hb[r];
      } else {
#pragma unroll
        for (int r = 0; r < 4; ++r)
          out[((size_t)(bq + r) * 1024 + ot) * 512 + d * 256 + jj] = hv[r];
      }
      if (t == 1023){
#pragma unroll
        for (int r = 0; r < 4; ++r){
          size_t bo = (size_t)(layer * 32 + bq + r) * 512 + d * 256 + jj;
          hnout[bo] = hv[r];
          cnout[bo] = cst[r];
        }
      }
    }
  }
}

extern "C" void kernel_launch(void* const* d_in, const int* in_sizes, int n_in,
                              void* d_out, int out_size, void* d_ws, size_t ws_size,
                              hipStream_t stream){
  const float* inputs  = (const float*)d_in[0];
  const float* mask    = (const float*)d_in[1];
  const float* l0f_Wih = (const float*)d_in[2];
  const float* l0f_Whh = (const float*)d_in[3];
  const float* l0f_bih = (const float*)d_in[4];
  const float* l0f_bhh = (const float*)d_in[5];
  const float* l0b_Wih = (const float*)d_in[6];
  const float* l0b_Whh = (const float*)d_in[7];
  const float* l0b_bih = (const float*)d_in[8];
  const float* l0b_bhh = (const float*)d_in[9];
  const float* l1f_Wih = (const float*)d_in[10];
  const float* l1f_Whh = (const float*)d_in[11];
  const float* l1f_bih = (const float*)d_in[12];
  const float* l1f_bhh = (const float*)d_in[13];
  const float* l1b_Wih = (const float*)d_in[14];
  const float* l1b_Whh = (const float*)d_in[15];
  const float* l1b_bih = (const float*)d_in[16];
  const float* l1b_bhh = (const float*)d_in[17];

  char* ws = (char*)d_ws;
  unsigned short* xg   = (unsigned short*)(ws);                 // [1024][2048][32] bf16, 134217728 B
  unsigned short* xbf  = (unsigned short*)(ws + 134217728);     // [32768][256]  bf16, 16777216 B
  unsigned short* hout = (unsigned short*)(ws + 150994944);     // [32768][512]  bf16, 33554432 B
  unsigned short* B0   = (unsigned short*)(ws + 184549376);     // [2048][256]   bf16, 1048576 B
  unsigned short* B1   = (unsigned short*)(ws + 185597952);     // [2048][512]   bf16, 2097152 B
  float* bias0         = (float*)(ws + 187695104);              // [2048] f32
  float* bias1         = (float*)(ws + 187703296);              // [2048] f32
  unsigned* hx         = (unsigned*)(ws + 187711488);           // 2 layers x [8][2][8][256] u32 = 262144 B

  float* out   = (float*)d_out;          // [32][1024][512]
  float* hnout = out + 16777216;         // [2][32][512]
  float* cnout = hnout + 32768;          // [2][32][512]

  hipMemsetAsync(hx, 0, 262144, stream);  // tag16 = 0, never matches tags 1..1024
  cast_x<<<32768, 64, 0, stream>>>(inputs, xbf);
  cast_w<<<2048, 64, 0, stream>>>(l0f_Wih, l0b_Wih, l0f_bih, l0f_bhh, l0b_bih, l0b_bhh, B0, bias0, 256);
  cast_w<<<2048, 64, 0, stream>>>(l1f_Wih, l1b_Wih, l1f_bih, l1f_bhh, l1b_bih, l1b_bhh, B1, bias1, 512);
  gemm_xg<<<4096, 256, 0, stream>>>(xbf, B0, bias0, xg, 256);
  lstm_rec<<<32, 256, 0, stream>>>(xg, l0f_Whh, l0b_Whh, mask, hx, hout, nullptr, hnout, cnout, 0);
  gemm_xg<<<4096, 256, 0, stream>>>(hout, B1, bias1, xg, 512);
  lstm_rec<<<32, 256, 0, stream>>>(xg, l1f_Whh, l1b_Whh, mask, hx + 32768, nullptr, out, hnout, cnout, 1);
}